// Round 2
// baseline (1217.622 us; speedup 1.0000x reference)
//
#include <hip/hip_runtime.h>
#include <stdint.h>

// Problem geometry (fixed by the reference).
#define M_DIM 4096      // BATCH * SEQ
#define N_DIM 16384     // OUT_FEATURES
#define K_DIM 4096      // IN_FEATURES

#define BM 128
#define BN 128
#define BK 64

typedef __attribute__((ext_vector_type(8))) short bf16x8;
typedef __attribute__((ext_vector_type(4))) float f32x4;

// ---------- helpers ----------

// fp32 -> bf16 bits, round-to-nearest-even (matches __float2bfloat16 for finite vals)
static __device__ __forceinline__ unsigned short f2bf(float f) {
    unsigned int u = __float_as_uint(f);
    return (unsigned short)((u + 0x7FFFu + ((u >> 16) & 1u)) >> 16);
}

typedef __attribute__((address_space(3))) void lds_void_t;
typedef const __attribute__((address_space(1))) void gbl_void_t;

// async global->LDS, 16B per lane. LDS dest must be wave-uniform base; HW adds lane*16.
static __device__ __forceinline__ void gload_lds16(const void* g, void* s) {
    __builtin_amdgcn_global_load_lds((gbl_void_t*)g, (lds_void_t*)s, 16, 0, 0);
}

// ---------- conversion kernels ----------

// x: fp32 [M][K] -> bf16 bits [M][K]; 8 elems/thread
__global__ void cvt_x_kernel(const float* __restrict__ x,
                             unsigned short* __restrict__ xb, int n8) {
    int i = blockIdx.x * blockDim.x + threadIdx.x;
    if (i >= n8) return;
    const float4 v0 = ((const float4*)x)[2 * i + 0];
    const float4 v1 = ((const float4*)x)[2 * i + 1];
    uint4 pk;
    pk.x = (unsigned)f2bf(v0.x) | ((unsigned)f2bf(v0.y) << 16);
    pk.y = (unsigned)f2bf(v0.z) | ((unsigned)f2bf(v0.w) << 16);
    pk.z = (unsigned)f2bf(v1.x) | ((unsigned)f2bf(v1.y) << 16);
    pk.w = (unsigned)f2bf(v1.z) | ((unsigned)f2bf(v1.w) << 16);
    ((uint4*)xb)[i] = pk;
}

// weight: fp32 [N][K] -> 2:4-masked bf16 bits [N][K]; one group of 4 per thread.
// Mask recomputed exactly as JAX: stable argsort of |w| ascending, keep rank>=2.
__global__ void cvt_w_kernel(const float* __restrict__ w,
                             unsigned short* __restrict__ wb, int ngroups) {
    int g = blockIdx.x * blockDim.x + threadIdx.x;
    if (g >= ngroups) return;
    const float4 v = ((const float4*)w)[g];
    float a0 = fabsf(v.x), a1 = fabsf(v.y), a2 = fabsf(v.z), a3 = fabsf(v.w);
    // stable-sort rank: #{j: a_j < a_i} + #{j<i: a_j == a_i}
    int r0 = (a1 < a0) + (a2 < a0) + (a3 < a0);
    int r1 = (a0 < a1) + (a2 < a1) + (a3 < a1) + (a0 == a1);
    int r2 = (a0 < a2) + (a1 < a2) + (a3 < a2) + (a0 == a2) + (a1 == a2);
    int r3 = (a0 < a3) + (a1 < a3) + (a2 < a3) + (a0 == a3) + (a1 == a3) + (a2 == a3);
    unsigned short o0 = (r0 >= 2) ? f2bf(v.x) : (unsigned short)0;
    unsigned short o1 = (r1 >= 2) ? f2bf(v.y) : (unsigned short)0;
    unsigned short o2 = (r2 >= 2) ? f2bf(v.z) : (unsigned short)0;
    unsigned short o3 = (r3 >= 2) ? f2bf(v.w) : (unsigned short)0;
    uint2 pk;
    pk.x = (unsigned)o0 | ((unsigned)o1 << 16);
    pk.y = (unsigned)o2 | ((unsigned)o3 << 16);
    ((uint2*)wb)[g] = pk;
}

// ---------- main GEMM: C[M][N] = A[M][K] * B[N][K]^T + bias ----------
// m97 structure: 128x128 tile, 4 waves (2x2), 4x4 16x16x32 fragments per wave,
// BK=64, global_load_lds width=16, XOR chunk swizzle (source-side + read-side).

__global__ __launch_bounds__(256)
void gemm_bt_kernel(const unsigned short* __restrict__ A,   // bf16 bits [M][K]
                    const unsigned short* __restrict__ B,   // bf16 bits [N][K]
                    const float* __restrict__ bias,
                    float* __restrict__ C) {
    __shared__ unsigned short As[BM * BK];   // [128][64], chunk-swizzled
    __shared__ unsigned short Bs[BN * BK];

    const int tid  = threadIdx.x;
    const int lane = tid & 63;
    const int wv   = tid >> 6;            // 0..3
    const int wm   = (wv >> 1) * 64;      // wave row offset in tile
    const int wn   = (wv & 1) * 64;       // wave col offset in tile

    // bijective XCD swizzle: nwg = 4096, divisible by 8
    const int nper = gridDim.x >> 3;
    int bid = blockIdx.x;
    int wg  = (bid & 7) * nper + (bid >> 3);
    const int tm = (wg >> 7) * BM;        // 128 tiles along N => wg&127
    const int tn = (wg & 127) * BN;

    // ---- staging geometry ----
    // LDS is 16 blocks of 1KB (8 rows x 64 cols bf16). Wave wv owns blocks wv*4+r.
    // Within a block: lane l writes 16B at row sub=l>>3, physical chunk p=l&7.
    // Swizzle: logical chunk stored at p = c ^ (row&7)  =>  source reads c = p ^ sub.
    const int sub  = lane >> 3;           // 0..7
    const int clog = (lane & 7) ^ sub;    // logical 16B chunk this lane fetches

    const unsigned short* a_src[4];
    const unsigned short* b_src[4];
#pragma unroll
    for (int r = 0; r < 4; ++r) {
        int row = (wv * 4 + r) * 8 + sub;                 // row within tile
        a_src[r] = A + (size_t)(tm + row) * K_DIM + clog * 8;
        b_src[r] = B + (size_t)(tn + row) * K_DIM + clog * 8;
    }

    const int frow = lane & 15;           // fragment row (A) / col (B,C)
    const int fk   = lane >> 4;           // 0..3: k-chunk within 32

    f32x4 acc[4][4] = {};

    for (int k0 = 0; k0 < K_DIM; k0 += BK) {
#pragma unroll
        for (int r = 0; r < 4; ++r) {
            gload_lds16(a_src[r], &As[(wv * 4 + r) * 512]);
            gload_lds16(b_src[r], &Bs[(wv * 4 + r) * 512]);
            a_src[r] += BK;
            b_src[r] += BK;
        }
        __syncthreads();   // drains vmcnt -> staged data visible

#pragma unroll
        for (int kk = 0; kk < 2; ++kk) {
            bf16x8 af[4], bfr[4];
#pragma unroll
            for (int i = 0; i < 4; ++i) {
                int c = kk * 4 + fk;                      // logical chunk 0..7
                int ra = wm + i * 16 + frow;
                int pa = c ^ (ra & 7);
                af[i] = *(const bf16x8*)&As[ra * BK + pa * 8];
                int rb = wn + i * 16 + frow;
                int pb = c ^ (rb & 7);
                bfr[i] = *(const bf16x8*)&Bs[rb * BK + pb * 8];
            }
#pragma unroll
            for (int i = 0; i < 4; ++i)
#pragma unroll
                for (int j = 0; j < 4; ++j)
                    acc[i][j] = __builtin_amdgcn_mfma_f32_16x16x32_bf16(
                        af[i], bfr[j], acc[i][j], 0, 0, 0);
        }
        __syncthreads();   // all waves done reading before next overwrite
    }

    // epilogue: C/D layout col = lane&15, row = (lane>>4)*4 + reg
    const int orow0 = tm + wm;
    const int ocol0 = tn + wn;
#pragma unroll
    for (int j = 0; j < 4; ++j) {
        int col = ocol0 + j * 16 + frow;
        float bj = bias[col];
#pragma unroll
        for (int i = 0; i < 4; ++i) {
            int rbase = orow0 + i * 16 + fk * 4;
            f32x4 v = acc[i][j];
#pragma unroll
            for (int r = 0; r < 4; ++r)
                C[(size_t)(rbase + r) * N_DIM + col] = v[r] + bj;
        }
    }
}

// ---------- fp32 fallback (only if ws too small) ----------
// grid: (N blocks) x (M/256 m-tiles); thread t of block (n, mt) computes out[mt*256+t][n].
__global__ void naive_kernel(const float* __restrict__ x, const float* __restrict__ w,
                             const float* __restrict__ bias, float* __restrict__ out) {
    int n  = blockIdx.x;
    int m  = blockIdx.y * 256 + threadIdx.x;
    const float4* xr = (const float4*)(x + (size_t)m * K_DIM);
    const float4* wr = (const float4*)(w + (size_t)n * K_DIM);
    float s = 0.f;
    for (int g = 0; g < K_DIM / 4; ++g) {
        float4 wv = wr[g];
        float4 xv = xr[g];
        float a0 = fabsf(wv.x), a1 = fabsf(wv.y), a2 = fabsf(wv.z), a3 = fabsf(wv.w);
        int r0 = (a1 < a0) + (a2 < a0) + (a3 < a0);
        int r1 = (a0 < a1) + (a2 < a1) + (a3 < a1) + (a0 == a1);
        int r2 = (a0 < a2) + (a1 < a2) + (a3 < a2) + (a0 == a2) + (a1 == a2);
        int r3 = (a0 < a3) + (a1 < a3) + (a2 < a3) + (a0 == a3) + (a1 == a3) + (a2 == a3);
        if (r0 >= 2) s += xv.x * wv.x;
        if (r1 >= 2) s += xv.y * wv.y;
        if (r2 >= 2) s += xv.z * wv.z;
        if (r3 >= 2) s += xv.w * wv.w;
    }
    out[(size_t)m * N_DIM + n] = s + bias[n];
}

// ---------- launch ----------
extern "C" void kernel_launch(void* const* d_in, const int* in_sizes, int n_in,
                              void* d_out, int out_size, void* d_ws, size_t ws_size,
                              hipStream_t stream) {
    const float* x    = (const float*)d_in[0];
    const float* w    = (const float*)d_in[1];
    // d_in[2] (mask) intentionally unused: recomputed exactly from weight.
    const float* bias = (const float*)d_in[3];
    float* out        = (float*)d_out;

    const size_t x_elems = (size_t)M_DIM * K_DIM;
    const size_t w_elems = (size_t)N_DIM * K_DIM;
    const size_t need    = (x_elems + w_elems) * sizeof(unsigned short);

    if (ws_size >= need) {
        unsigned short* xb = (unsigned short*)d_ws;
        unsigned short* wb = xb + x_elems;

        int n8 = (int)(x_elems / 8);
        cvt_x_kernel<<<(n8 + 255) / 256, 256, 0, stream>>>(x, xb, n8);
        int ng = (int)(w_elems / 4);
        cvt_w_kernel<<<(ng + 255) / 256, 256, 0, stream>>>(w, wb, ng);

        dim3 grid((M_DIM / BM) * (N_DIM / BN));   // 32 * 128 = 4096
        gemm_bt_kernel<<<grid, 256, 0, stream>>>(xb, wb, bias, out);
    } else {
        dim3 grid(N_DIM, M_DIM / 256);
        naive_kernel<<<grid, 256, 0, stream>>>(x, w, bias, out);
    }
}